// Round 1
// 370.081 us; speedup vs baseline: 1.1037x; 1.1037x over previous
//
#include <hip/hip_runtime.h>

#define HWB   3136
#define HWPAD 3200
#define SPAD  3364   // 58*58 zero-padded spatial

typedef __attribute__((ext_vector_type(8))) short bf16x8;
typedef __attribute__((ext_vector_type(4))) float f32x4;

__device__ __forceinline__ unsigned short f2bf(float f) {
    unsigned u = __float_as_uint(f);
    unsigned r = (u + 0x7fffu + ((u >> 16) & 1u)) >> 16;
    return (unsigned short)r;
}
__device__ __forceinline__ float bf2f(unsigned short h) {
    return __uint_as_float(((unsigned)h) << 16);
}
__device__ __forceinline__ void gl_lds16(const void* g, void* l) {
    __builtin_amdgcn_global_load_lds(
        (const __attribute__((address_space(1))) void*)g,
        (__attribute__((address_space(3))) void*)l, 16, 0, 0);
}

// ---------------------------------------------------------------------------
// Prep: x [32][256][3136] f32 -> xc [32][256][3136] bf16 (same layout)
//                             -> xp [32][3364][256] bf16 (padded channels-last)
// interior only; border rows zeroed by k_prep_w.
// ---------------------------------------------------------------------------
__global__ __launch_bounds__(256) void k_prep(
    const float* __restrict__ x, unsigned short* __restrict__ xc,
    unsigned short* __restrict__ xp)
{
    __shared__ unsigned short tile[32][33];
    const int n = blockIdx.z, c0 = blockIdx.y * 32, s0 = blockIdx.x * 32;
    const int lx = threadIdx.x & 31, ly = threadIdx.x >> 5;
    const float* xb = x + ((size_t)(n * 256 + c0)) * HWB + s0;
    unsigned short* xcb = xc + ((size_t)(n * 256 + c0)) * HWB + s0;
#pragma unroll
    for (int it = 0; it < 4; ++it) {
        int lc = ly + it * 8;
        unsigned short b = f2bf(xb[(size_t)lc * HWB + lx]);
        tile[lc][lx] = b;
        xcb[(size_t)lc * HWB + lx] = b;
    }
    __syncthreads();
    unsigned short* ob = xp + (size_t)n * SPAD * 256 + c0;
#pragma unroll
    for (int it = 0; it < 4; ++it) {
        int ls = ly + it * 8;
        int s = s0 + ls;
        int sp = s + 2 * (s / 56) + 59;   // (y+1)*58 + (x+1)
        ob[(size_t)sp * 256 + lx] = tile[lx][ls];
    }
}

// ---------------------------------------------------------------------------
// Prep B: p1 [3136][256] f32 -> p1t [256][3136] bf16
// ---------------------------------------------------------------------------
__global__ __launch_bounds__(256) void k_prep_p1t(
    const float* __restrict__ p1, unsigned short* __restrict__ p1t)
{
    __shared__ unsigned short tile[32][33];
    const int e0 = blockIdx.y * 32, h0 = blockIdx.x * 32;
    const int lx = threadIdx.x & 31, ly = threadIdx.x >> 5;
#pragma unroll
    for (int it = 0; it < 4; ++it) {
        int lh = ly + it * 8;
        tile[lh][lx] = f2bf(p1[(size_t)(h0 + lh) * 256 + e0 + lx]);
    }
    __syncthreads();
#pragma unroll
    for (int it = 0; it < 4; ++it) {
        int le = ly + it * 8;
        p1t[(size_t)(e0 + le) * HWB + h0 + lx] = tile[lx][le];
    }
}

// ---------------------------------------------------------------------------
// Prep C: conv_w [256][128][9] f32 -> wpack [256][tap*128+ci] bf16.
// Blocks o<32 additionally zero the 228 border positions of xp for n=o.
// ---------------------------------------------------------------------------
__global__ __launch_bounds__(256) void k_prep_w(
    const float* __restrict__ w, unsigned short* __restrict__ wp,
    unsigned short* __restrict__ xp)
{
    const int o = blockIdx.x, t = threadIdx.x;
#pragma unroll
    for (int k = t; k < 1152; k += 256) {
        int tap = k >> 7, ci = k & 127;
        wp[(size_t)o * 1152 + k] = f2bf(w[(size_t)o * 1152 + ci * 9 + tap]);
    }
    if (o < 32) {
        unsigned short* xpn = xp + (size_t)o * SPAD * 256;
        for (int sp = t; sp < SPAD; sp += 256) {
            int y = sp / 58, xcol = sp - y * 58;
            if (y == 0 || y == 57 || xcol == 0 || xcol == 57) {
                ushort4 z4 = {0, 0, 0, 0};
#pragma unroll
                for (int k = 0; k < 64; ++k)
                    *(ushort4*)&xpn[(size_t)sp * 256 + k * 4] = z4;
            }
        }
    }
}

// ---------------------------------------------------------------------------
// Conv (grouped 3x3) MFMA GEMM per (n,g): D[m=s][n=o], K = 9 taps * 128 ci.
// Padded input -> no predicates; fully unrolled K loop with constant shifts.
// Output channels-last: t3cl[n][s][c] bf16 (pad rows zeroed).
// ---------------------------------------------------------------------------
__global__ __launch_bounds__(256) void k_conv(
    const unsigned short* __restrict__ xp, const unsigned short* __restrict__ wp,
    unsigned short* __restrict__ t3cl)
{
    __shared__ short As[128 * 64];
    __shared__ short Bs[128 * 64];
    const int tid = threadIdx.x;
    const int n = blockIdx.y >> 1, g = blockIdx.y & 1;
    const int tileS = blockIdx.x * 128;
    const int wave = tid >> 6, lane = tid & 63;
    const int wm = (wave >> 1) * 64, wn = (wave & 1) * 64;

    const int rl = tid >> 3, q = tid & 7;
    const int swq = (q ^ (rl & 7)) * 8;     // pre-swizzled source chunk (shorts)

    const unsigned short* xpn = xp + (size_t)n * SPAD * 256 + g * 128 + swq;
    const unsigned short* arow[4];
    const unsigned short* brow[4];
#pragma unroll
    for (int p = 0; p < 4; ++p) {
        int s = tileS + p * 32 + rl;
        int sc = s < HWB ? s : HWB - 1;     // clamped rows feed discarded outputs
        int sp = sc + 2 * (sc / 56) + 59;
        arow[p] = xpn + (size_t)sp * 256;
        brow[p] = wp + (size_t)(g * 128 + p * 32 + rl) * 1152 + swq;
    }

    f32x4 acc[4][4] = {};
    const int frow = lane & 15, quad = lane >> 4, sw = frow & 7;
    int rofA[4], rofB[4];
#pragma unroll
    for (int i = 0; i < 4; ++i) {
        rofA[i] = (wm + i * 16 + frow) * 64;
        rofB[i] = (wn + i * 16 + frow) * 64;
    }

#pragma unroll
    for (int t = 0; t < 18; ++t) {
        const int tap = t >> 1;
        const int shift = ((tap / 3 - 1) * 58 + (tap % 3 - 1)) * 256 + (t & 1) * 64;
        __syncthreads();
#pragma unroll
        for (int p = 0; p < 4; ++p) {
            gl_lds16(arow[p] + shift, &As[(p * 32 + rl) * 64 + q * 8]);
            gl_lds16(brow[p] + t * 64, &Bs[(p * 32 + rl) * 64 + q * 8]);
        }
        __syncthreads();
#pragma unroll
        for (int h = 0; h < 2; ++h) {
            bf16x8 af[4], bfr[4];
#pragma unroll
            for (int i = 0; i < 4; ++i)
                af[i] = *(const bf16x8*)&As[rofA[i] + ((h * 4 + quad) ^ sw) * 8];
#pragma unroll
            for (int j = 0; j < 4; ++j)
                bfr[j] = *(const bf16x8*)&Bs[rofB[j] + ((h * 4 + quad) ^ sw) * 8];
#pragma unroll
            for (int i = 0; i < 4; ++i)
#pragma unroll
                for (int j = 0; j < 4; ++j)
                    acc[i][j] = __builtin_amdgcn_mfma_f32_16x16x32_bf16(af[i], bfr[j], acc[i][j], 0, 0, 0);
        }
    }
    unsigned short* ob = t3cl + (size_t)n * HWPAD * 256 + g * 128;
#pragma unroll
    for (int i = 0; i < 4; ++i)
#pragma unroll
        for (int r = 0; r < 4; ++r) {
            int s = tileS + wm + i * 16 + (lane >> 4) * 4 + r;
            int c = wn + (lane & 15);
#pragma unroll
            for (int j = 0; j < 4; ++j) {
                float v = (s < HWB) ? acc[i][j][r] : 0.f;
                ob[(size_t)s * 256 + c + j * 16] = f2bf(v);
            }
        }
}

// ---------------------------------------------------------------------------
// GEMM1 (split-K=4, BK=64): part[z][m][e] = sum_k xc[m][k] p1t[e][k]
// Both operands bf16 via global_load_lds; plain stores (no atomics).
// K slices: z=0 -> 13 steps (832), z=1..3 -> 12 steps (768).
// ---------------------------------------------------------------------------
__global__ __launch_bounds__(256) void k_gemm1(
    const unsigned short* __restrict__ xc, const unsigned short* __restrict__ p1t,
    float* __restrict__ part)
{
    __shared__ short As[128 * 64];
    __shared__ short Bs[128 * 64];
    const int tid = threadIdx.x;
    const int z = blockIdx.z;
    const int tileM = blockIdx.y * 128;
    const int tileN = blockIdx.x * 128;
    const int kbase = z ? (832 + (z - 1) * 768) : 0;
    const int nk = z ? 12 : 13;
    const int wave = tid >> 6, lane = tid & 63;
    const int wm = (wave >> 1) * 64, wn = (wave & 1) * 64;

    const int rl = tid >> 3, q = tid & 7;
    const int swq = (q ^ (rl & 7)) * 8;
    const unsigned short* asrc = xc + (size_t)(tileM + rl) * HWB + kbase + swq;
    const unsigned short* bsrc = p1t + (size_t)(tileN + rl) * HWB + kbase + swq;

    f32x4 acc[4][4] = {};
    const int frow = lane & 15, quad = lane >> 4, sw = frow & 7;

    for (int k0 = 0; k0 < nk * 64; k0 += 64) {
        __syncthreads();
#pragma unroll
        for (int p = 0; p < 4; ++p) {
            gl_lds16(asrc + (size_t)(p * 32) * HWB + k0, &As[(p * 32 + rl) * 64 + q * 8]);
            gl_lds16(bsrc + (size_t)(p * 32) * HWB + k0, &Bs[(p * 32 + rl) * 64 + q * 8]);
        }
        __syncthreads();
#pragma unroll
        for (int h = 0; h < 2; ++h) {
            bf16x8 af[4], bfr[4];
#pragma unroll
            for (int i = 0; i < 4; ++i)
                af[i] = *(const bf16x8*)&As[(wm + i * 16 + frow) * 64 + ((h * 4 + quad) ^ sw) * 8];
#pragma unroll
            for (int j = 0; j < 4; ++j)
                bfr[j] = *(const bf16x8*)&Bs[(wn + j * 16 + frow) * 64 + ((h * 4 + quad) ^ sw) * 8];
#pragma unroll
            for (int i = 0; i < 4; ++i)
#pragma unroll
                for (int j = 0; j < 4; ++j)
                    acc[i][j] = __builtin_amdgcn_mfma_f32_16x16x32_bf16(af[i], bfr[j], acc[i][j], 0, 0, 0);
        }
    }
    float* ob = part + (size_t)z * 8192 * 256;
#pragma unroll
    for (int j = 0; j < 4; ++j) {
        const int e = tileN + wn + j * 16 + (lane & 15);
#pragma unroll
        for (int i = 0; i < 4; ++i)
#pragma unroll
            for (int r = 0; r < 4; ++r) {
                int m = tileM + wm + i * 16 + (lane >> 4) * 4 + r;
                ob[(size_t)m * 256 + e] = acc[i][j][r];
            }
    }
}

// ---------------------------------------------------------------------------
// t4scale: reduce 4 split-K slabs; t4h[m][e] = bf16(t1*p4); t5[m]=sum_e t4*p5
// ---------------------------------------------------------------------------
__global__ __launch_bounds__(256) void k_t4scale(
    const float* __restrict__ part, const float* __restrict__ p4,
    const float* __restrict__ p5, unsigned short* __restrict__ t4h,
    float* __restrict__ t5)
{
    const int row = blockIdx.x * 4 + (threadIdx.x >> 6);
    const int lane = threadIdx.x & 63;
    const size_t off = (size_t)row * 256 + lane * 4;
    const size_t slab = (size_t)8192 * 256;
    float4 a0 = *(const float4*)&part[off];
    float4 a1 = *(const float4*)&part[off + slab];
    float4 a2 = *(const float4*)&part[off + 2 * slab];
    float4 a3 = *(const float4*)&part[off + 3 * slab];
    float4 a;
    a.x = (a0.x + a1.x) + (a2.x + a3.x);
    a.y = (a0.y + a1.y) + (a2.y + a3.y);
    a.z = (a0.z + a1.z) + (a2.z + a3.z);
    a.w = (a0.w + a1.w) + (a2.w + a3.w);
    float4 sc = *(const float4*)&p4[(size_t)(row & 255) * 256 + lane * 4];
    float4 pv = *(const float4*)&p5[lane * 4];
    float v0 = a.x * sc.x, v1 = a.y * sc.y, v2 = a.z * sc.z, v3 = a.w * sc.w;
    ushort4 o;
    o.x = f2bf(v0); o.y = f2bf(v1); o.z = f2bf(v2); o.w = f2bf(v3);
    *(ushort4*)&t4h[(size_t)row * 256 + lane * 4] = o;
    float sum = v0 * pv.x + v1 * pv.y + v2 * pv.z + v3 * pv.w;
#pragma unroll
    for (int offd = 32; offd > 0; offd >>= 1) sum += __shfl_down(sum, offd);
    if (lane == 0) t5[row] = sum;
}

// ---------------------------------------------------------------------------
// t7[n][s] = (sum_c t5[n*256+c] * xp[n][sp(s)][c]) / 16
// ---------------------------------------------------------------------------
__global__ __launch_bounds__(256) void k_t7(
    const unsigned short* __restrict__ xp, const float* __restrict__ t5,
    float* __restrict__ t7)
{
    const int n = blockIdx.y;
    const int wave = threadIdx.x >> 6, lane = threadIdx.x & 63;
    float4 w = *(const float4*)&t5[n * 256 + lane * 4];
    const int s0 = blockIdx.x * 16 + wave * 4;
#pragma unroll
    for (int qq = 0; qq < 4; ++qq) {
        const int s = s0 + qq;
        const int sp = s + 2 * (s / 56) + 59;
        ushort4 a = *(const ushort4*)&xp[((size_t)n * SPAD + sp) * 256 + lane * 4];
        float sum = bf2f(a.x) * w.x + bf2f(a.y) * w.y + bf2f(a.z) * w.z + bf2f(a.w) * w.w;
#pragma unroll
        for (int off = 32; off > 0; off >>= 1) sum += __shfl_down(sum, off);
        if (lane == 0) t7[n * HWB + s] = sum * 0.0625f;
    }
}

// ---------------------------------------------------------------------------
// BMM: out[n][a][s] = (sum_b t4h[n][a][b] * t3cl[n][s][b]) / 16 + t7[n][s]
// ---------------------------------------------------------------------------
__global__ __launch_bounds__(256) void k_bmm(
    const unsigned short* __restrict__ t4h, const unsigned short* __restrict__ t3cl,
    const float* __restrict__ t7, float* __restrict__ out)
{
    __shared__ short As[128 * 64];
    __shared__ short Bs[128 * 64];
    const int tid = threadIdx.x;
    const int n = blockIdx.z;
    const int tileA = blockIdx.y * 128;
    const int tileS = blockIdx.x * 128;
    const int wave = tid >> 6, lane = tid & 63;
    const int wm = (wave >> 1) * 64, wn = (wave & 1) * 64;

    const int rl = tid >> 3, q = tid & 7;
    const int swq = (q ^ (rl & 7)) * 8;
    const unsigned short* asrc = t4h + ((size_t)n * 256 + tileA + rl) * 256 + swq;
    const unsigned short* bsrc = t3cl + ((size_t)n * HWPAD + tileS + rl) * 256 + swq;

    f32x4 acc[4][4] = {};
    const int frow = lane & 15, quad = lane >> 4, sw = frow & 7;

    for (int k0 = 0; k0 < 256; k0 += 64) {
        __syncthreads();
#pragma unroll
        for (int p = 0; p < 4; ++p) {
            gl_lds16(asrc + (size_t)(p * 32) * 256 + k0, &As[(p * 32 + rl) * 64 + q * 8]);
            gl_lds16(bsrc + (size_t)(p * 32) * 256 + k0, &Bs[(p * 32 + rl) * 64 + q * 8]);
        }
        __syncthreads();
#pragma unroll
        for (int h = 0; h < 2; ++h) {
            bf16x8 af[4], bfr[4];
#pragma unroll
            for (int i = 0; i < 4; ++i)
                af[i] = *(const bf16x8*)&As[(wm + i * 16 + frow) * 64 + ((h * 4 + quad) ^ sw) * 8];
#pragma unroll
            for (int j = 0; j < 4; ++j)
                bfr[j] = *(const bf16x8*)&Bs[(wn + j * 16 + frow) * 64 + ((h * 4 + quad) ^ sw) * 8];
#pragma unroll
            for (int i = 0; i < 4; ++i)
#pragma unroll
                for (int j = 0; j < 4; ++j)
                    acc[i][j] = __builtin_amdgcn_mfma_f32_16x16x32_bf16(af[i], bfr[j], acc[i][j], 0, 0, 0);
        }
    }
    const float* t7n = t7 + (size_t)n * HWB;
    float* ob = out + (size_t)n * 256 * HWB;
#pragma unroll
    for (int j = 0; j < 4; ++j) {
        int s = tileS + wn + j * 16 + (lane & 15);
        bool vsx = s < HWB;
        float t7v = vsx ? t7n[s] : 0.f;
        if (!vsx) continue;
#pragma unroll
        for (int i = 0; i < 4; ++i)
#pragma unroll
            for (int r = 0; r < 4; ++r) {
                int a = tileA + wm + i * 16 + (lane >> 4) * 4 + r;
                ob[(size_t)a * HWB + s] = acc[i][j][r] * 0.0625f + t7v;
            }
    }
}

extern "C" void kernel_launch(void* const* d_in, const int* in_sizes, int n_in,
                              void* d_out, int out_size, void* d_ws, size_t ws_size,
                              hipStream_t stream) {
    const float* x  = (const float*)d_in[0];
    const float* p1 = (const float*)d_in[1];
    const float* cw = (const float*)d_in[2];
    const float* p4 = (const float*)d_in[3];
    const float* p5 = (const float*)d_in[4];

    char* w = (char*)d_ws;
    unsigned short* xp    = (unsigned short*)w;  w += (size_t)32 * SPAD * 256 * 2;   // 55.1 MB
    unsigned short* t3cl  = (unsigned short*)w;  w += (size_t)32 * HWPAD * 256 * 2;  // 52.4 MB
    unsigned short* p1t   = (unsigned short*)w;  w += (size_t)256 * HWB * 2;
    unsigned short* wpack = (unsigned short*)w;  w += (size_t)256 * 1152 * 2;
    unsigned short* t4h   = (unsigned short*)w;  w += (size_t)8192 * 256 * 2;
    float* t5             = (float*)w;           w += (size_t)8192 * 4;
    float* t7             = (float*)w;           w += (size_t)32 * HWB * 4;

    // d_out doubles as scratch before k_bmm finally writes it:
    //   xc   [32][256][3136] bf16 = 51,380,224 B
    //   part [4][8192][256]  f32  = 33,554,432 B  (total 84.9 MB <= 102.8 MB)
    char* o = (char*)d_out;
    unsigned short* xc = (unsigned short*)o;
    float* part        = (float*)(o + (size_t)32 * 256 * HWB * 2);
    float* out = (float*)d_out;

    k_prep    <<<dim3(98, 8, 32), 256, 0, stream>>>(x, xc, xp);
    k_prep_p1t<<<dim3(98, 8),     256, 0, stream>>>(p1, p1t);
    k_prep_w  <<<dim3(256),       256, 0, stream>>>(cw, wpack, xp);
    k_conv    <<<dim3(25, 64),    256, 0, stream>>>(xp, wpack, t3cl);
    k_gemm1   <<<dim3(2, 64, 4),  256, 0, stream>>>(xc, p1t, part);
    k_t4scale <<<dim3(2048),      256, 0, stream>>>(part, p4, p5, t4h, t5);
    k_t7      <<<dim3(196, 32),   256, 0, stream>>>(xp, t5, t7);
    k_bmm     <<<dim3(25, 2, 32), 256, 0, stream>>>(t4h, t3cl, t7, out);
}

// Round 2
// 368.508 us; speedup vs baseline: 1.1084x; 1.0043x over previous
//
#include <hip/hip_runtime.h>

#define HWB   3136
#define HWPAD 3200
#define SPAD  3364   // 58*58 zero-padded spatial

typedef __attribute__((ext_vector_type(8))) short bf16x8;
typedef __attribute__((ext_vector_type(4))) float f32x4;

__device__ __forceinline__ unsigned short f2bf(float f) {
    unsigned u = __float_as_uint(f);
    unsigned r = (u + 0x7fffu + ((u >> 16) & 1u)) >> 16;
    return (unsigned short)r;
}
__device__ __forceinline__ float bf2f(unsigned short h) {
    return __uint_as_float(((unsigned)h) << 16);
}
__device__ __forceinline__ void gl_lds16(const void* g, void* l) {
    __builtin_amdgcn_global_load_lds(
        (const __attribute__((address_space(1))) void*)g,
        (__attribute__((address_space(3))) void*)l, 16, 0, 0);
}

// ---------------------------------------------------------------------------
// Prep: x [32][256][3136] f32 -> xc [32][256][3136] bf16 (same layout)
//                             -> xp [32][3364][256] bf16 (padded channels-last)
// interior only; border rows zeroed by k_prep_w.
// ---------------------------------------------------------------------------
__global__ __launch_bounds__(256) void k_prep(
    const float* __restrict__ x, unsigned short* __restrict__ xc,
    unsigned short* __restrict__ xp)
{
    __shared__ unsigned short tile[32][33];
    const int n = blockIdx.z, c0 = blockIdx.y * 32, s0 = blockIdx.x * 32;
    const int lx = threadIdx.x & 31, ly = threadIdx.x >> 5;
    const float* xb = x + ((size_t)(n * 256 + c0)) * HWB + s0;
    unsigned short* xcb = xc + ((size_t)(n * 256 + c0)) * HWB + s0;
#pragma unroll
    for (int it = 0; it < 4; ++it) {
        int lc = ly + it * 8;
        unsigned short b = f2bf(xb[(size_t)lc * HWB + lx]);
        tile[lc][lx] = b;
        xcb[(size_t)lc * HWB + lx] = b;
    }
    __syncthreads();
    unsigned short* ob = xp + (size_t)n * SPAD * 256 + c0;
#pragma unroll
    for (int it = 0; it < 4; ++it) {
        int ls = ly + it * 8;
        int s = s0 + ls;
        int sp = s + 2 * (s / 56) + 59;   // (y+1)*58 + (x+1)
        ob[(size_t)sp * 256 + lx] = tile[lx][ls];
    }
}

// ---------------------------------------------------------------------------
// Prep B: p1 [3136][256] f32 -> p1t [256][3136] bf16
// ---------------------------------------------------------------------------
__global__ __launch_bounds__(256) void k_prep_p1t(
    const float* __restrict__ p1, unsigned short* __restrict__ p1t)
{
    __shared__ unsigned short tile[32][33];
    const int e0 = blockIdx.y * 32, h0 = blockIdx.x * 32;
    const int lx = threadIdx.x & 31, ly = threadIdx.x >> 5;
#pragma unroll
    for (int it = 0; it < 4; ++it) {
        int lh = ly + it * 8;
        tile[lh][lx] = f2bf(p1[(size_t)(h0 + lh) * 256 + e0 + lx]);
    }
    __syncthreads();
#pragma unroll
    for (int it = 0; it < 4; ++it) {
        int le = ly + it * 8;
        p1t[(size_t)(e0 + le) * HWB + h0 + lx] = tile[lx][le];
    }
}

// ---------------------------------------------------------------------------
// Prep C: conv_w [256][128][9] f32 -> wpack [256][tap*128+ci] bf16.
// Blocks o<32 additionally zero the 228 border positions of xp for n=o.
// ---------------------------------------------------------------------------
__global__ __launch_bounds__(256) void k_prep_w(
    const float* __restrict__ w, unsigned short* __restrict__ wp,
    unsigned short* __restrict__ xp)
{
    const int o = blockIdx.x, t = threadIdx.x;
#pragma unroll
    for (int k = t; k < 1152; k += 256) {
        int tap = k >> 7, ci = k & 127;
        wp[(size_t)o * 1152 + k] = f2bf(w[(size_t)o * 1152 + ci * 9 + tap]);
    }
    if (o < 32) {
        unsigned short* xpn = xp + (size_t)o * SPAD * 256;
        for (int sp = t; sp < SPAD; sp += 256) {
            int y = sp / 58, xcol = sp - y * 58;
            if (y == 0 || y == 57 || xcol == 0 || xcol == 57) {
                ushort4 z4 = {0, 0, 0, 0};
#pragma unroll
                for (int k = 0; k < 64; ++k)
                    *(ushort4*)&xpn[(size_t)sp * 256 + k * 4] = z4;
            }
        }
    }
}

// ---------------------------------------------------------------------------
// Conv (grouped 3x3) MFMA GEMM per (n,g): D[m=s][n=o], K = 9 taps * 128 ci.
// Padded input -> no predicates.  XCD-swizzled 1D grid (same-n blocks share
// an XCD's L2 across the 9 tap re-reads).  Double-buffered LDS: stage(t+1)
// issued before compute(t), one barrier per K-step.
// ---------------------------------------------------------------------------
__global__ __launch_bounds__(256) void k_conv(
    const unsigned short* __restrict__ xp, const unsigned short* __restrict__ wp,
    unsigned short* __restrict__ t3cl)
{
    __shared__ short As[2][128 * 64];
    __shared__ short Bs[2][128 * 64];
    const int tid = threadIdx.x;
    const int orig = blockIdx.x;                       // 1600 = 8 * 200
    const int wgid = (orig & 7) * 200 + (orig >> 3);   // bijective XCD chunks
    const int ng = wgid / 25;
    const int tileS = (wgid - ng * 25) * 128;
    const int n = ng >> 1, g = ng & 1;
    const int wave = tid >> 6, lane = tid & 63;
    const int wm = (wave >> 1) * 64, wn = (wave & 1) * 64;

    const int rl = tid >> 3, q = tid & 7;
    const int swq = (q ^ (rl & 7)) * 8;     // pre-swizzled source chunk (shorts)

    const unsigned short* xpn = xp + (size_t)n * SPAD * 256 + g * 128 + swq;
    const unsigned short* arow[4];
    const unsigned short* brow[4];
#pragma unroll
    for (int p = 0; p < 4; ++p) {
        int s = tileS + p * 32 + rl;
        int sc = s < HWB ? s : HWB - 1;     // clamped rows feed discarded outputs
        int sp = sc + 2 * (sc / 56) + 59;
        arow[p] = xpn + (size_t)sp * 256;
        brow[p] = wp + (size_t)(g * 128 + p * 32 + rl) * 1152 + swq;
    }

    f32x4 acc[4][4] = {};
    const int frow = lane & 15, quad = lane >> 4, sw = frow & 7;
    int rofA[4], rofB[4];
#pragma unroll
    for (int i = 0; i < 4; ++i) {
        rofA[i] = (wm + i * 16 + frow) * 64;
        rofB[i] = (wn + i * 16 + frow) * 64;
    }
    const int ldst = (tid >> 3) * 64 + (tid & 7) * 8;  // == rl*64 + q*8

    // prologue: stage t=0 into buffer 0
    {
        const int shift0 = (-59) * 256;   // tap 0: dy=-1,dx=-1, kc=0
#pragma unroll
        for (int p = 0; p < 4; ++p) {
            gl_lds16(arow[p] + shift0, &As[0][p * 2048 + ldst]);
            gl_lds16(brow[p], &Bs[0][p * 2048 + ldst]);
        }
    }
    __syncthreads();

    int cur = 0;
#pragma unroll
    for (int t = 0; t < 18; ++t) {
        if (t < 17) {
            const int tn = t + 1;
            const int tap = tn >> 1;
            const int shift = ((tap / 3 - 1) * 58 + (tap % 3 - 1)) * 256 + (tn & 1) * 64;
#pragma unroll
            for (int p = 0; p < 4; ++p) {
                gl_lds16(arow[p] + shift, &As[cur ^ 1][p * 2048 + ldst]);
                gl_lds16(brow[p] + tn * 64, &Bs[cur ^ 1][p * 2048 + ldst]);
            }
        }
        const short* Ab = As[cur];
        const short* Bb = Bs[cur];
#pragma unroll
        for (int h = 0; h < 2; ++h) {
            bf16x8 af[4], bfr[4];
#pragma unroll
            for (int i = 0; i < 4; ++i)
                af[i] = *(const bf16x8*)&Ab[rofA[i] + ((h * 4 + quad) ^ sw) * 8];
#pragma unroll
            for (int j = 0; j < 4; ++j)
                bfr[j] = *(const bf16x8*)&Bb[rofB[j] + ((h * 4 + quad) ^ sw) * 8];
#pragma unroll
            for (int i = 0; i < 4; ++i)
#pragma unroll
                for (int j = 0; j < 4; ++j)
                    acc[i][j] = __builtin_amdgcn_mfma_f32_16x16x32_bf16(af[i], bfr[j], acc[i][j], 0, 0, 0);
        }
        __syncthreads();
        cur ^= 1;
    }
    unsigned short* ob = t3cl + (size_t)n * HWPAD * 256 + g * 128;
#pragma unroll
    for (int i = 0; i < 4; ++i)
#pragma unroll
        for (int r = 0; r < 4; ++r) {
            int s = tileS + wm + i * 16 + (lane >> 4) * 4 + r;
            int c = wn + (lane & 15);
#pragma unroll
            for (int j = 0; j < 4; ++j) {
                float v = (s < HWB) ? acc[i][j][r] : 0.f;
                ob[(size_t)s * 256 + c + j * 16] = f2bf(v);
            }
        }
}

// ---------------------------------------------------------------------------
// GEMM1 (split-K=4, BK=64): part[z][m][e] = sum_k xc[m][k] p1t[e][k]
// Double-buffered staging; XCD swizzle keeps the (tileN=0,1) pair that shares
// an A-panel on the same XCD.  K slices: z=0 -> 13 steps, z=1..3 -> 12.
// ---------------------------------------------------------------------------
__global__ __launch_bounds__(256) void k_gemm1(
    const unsigned short* __restrict__ xc, const unsigned short* __restrict__ p1t,
    float* __restrict__ part)
{
    __shared__ short As[2][128 * 64];
    __shared__ short Bs[2][128 * 64];
    const int tid = threadIdx.x;
    const int orig = blockIdx.x;                      // 512 = 8 * 64
    const int wgid = (orig & 7) * 64 + (orig >> 3);
    const int z = wgid >> 7;
    const int rem = wgid & 127;
    const int tileM = (rem >> 1) * 128;
    const int tileN = (rem & 1) * 128;
    const int kbase = z ? (832 + (z - 1) * 768) : 0;
    const int nk = z ? 12 : 13;
    const int wave = tid >> 6, lane = tid & 63;
    const int wm = (wave >> 1) * 64, wn = (wave & 1) * 64;

    const int rl = tid >> 3, q = tid & 7;
    const int swq = (q ^ (rl & 7)) * 8;
    const unsigned short* asrc = xc + (size_t)(tileM + rl) * HWB + kbase + swq;
    const unsigned short* bsrc = p1t + (size_t)(tileN + rl) * HWB + kbase + swq;

    f32x4 acc[4][4] = {};
    const int frow = lane & 15, quad = lane >> 4, sw = frow & 7;
    const int ldst = rl * 64 + q * 8;

#pragma unroll
    for (int p = 0; p < 4; ++p) {
        gl_lds16(asrc + (size_t)(p * 32) * HWB, &As[0][p * 2048 + ldst]);
        gl_lds16(bsrc + (size_t)(p * 32) * HWB, &Bs[0][p * 2048 + ldst]);
    }
    __syncthreads();

    int cur = 0;
    for (int i2 = 0; i2 < nk; ++i2) {
        if (i2 + 1 < nk) {
            const int kn = (i2 + 1) * 64;
#pragma unroll
            for (int p = 0; p < 4; ++p) {
                gl_lds16(asrc + (size_t)(p * 32) * HWB + kn, &As[cur ^ 1][p * 2048 + ldst]);
                gl_lds16(bsrc + (size_t)(p * 32) * HWB + kn, &Bs[cur ^ 1][p * 2048 + ldst]);
            }
        }
        const short* Ab = As[cur];
        const short* Bb = Bs[cur];
#pragma unroll
        for (int h = 0; h < 2; ++h) {
            bf16x8 af[4], bfr[4];
#pragma unroll
            for (int i = 0; i < 4; ++i)
                af[i] = *(const bf16x8*)&Ab[(wm + i * 16 + frow) * 64 + ((h * 4 + quad) ^ sw) * 8];
#pragma unroll
            for (int j = 0; j < 4; ++j)
                bfr[j] = *(const bf16x8*)&Bb[(wn + j * 16 + frow) * 64 + ((h * 4 + quad) ^ sw) * 8];
#pragma unroll
            for (int i = 0; i < 4; ++i)
#pragma unroll
                for (int j = 0; j < 4; ++j)
                    acc[i][j] = __builtin_amdgcn_mfma_f32_16x16x32_bf16(af[i], bfr[j], acc[i][j], 0, 0, 0);
        }
        __syncthreads();
        cur ^= 1;
    }
    float* ob = part + (size_t)z * 8192 * 256;
#pragma unroll
    for (int j = 0; j < 4; ++j) {
        const int e = tileN + wn + j * 16 + (lane & 15);
#pragma unroll
        for (int i = 0; i < 4; ++i)
#pragma unroll
            for (int r = 0; r < 4; ++r) {
                int m = tileM + wm + i * 16 + (lane >> 4) * 4 + r;
                ob[(size_t)m * 256 + e] = acc[i][j][r];
            }
    }
}

// ---------------------------------------------------------------------------
// t4scale: reduce 4 split-K slabs; t4h[m][e] = bf16(t1*p4); t5[m]=sum_e t4*p5
// ---------------------------------------------------------------------------
__global__ __launch_bounds__(256) void k_t4scale(
    const float* __restrict__ part, const float* __restrict__ p4,
    const float* __restrict__ p5, unsigned short* __restrict__ t4h,
    float* __restrict__ t5)
{
    const int row = blockIdx.x * 4 + (threadIdx.x >> 6);
    const int lane = threadIdx.x & 63;
    const size_t off = (size_t)row * 256 + lane * 4;
    const size_t slab = (size_t)8192 * 256;
    float4 a0 = *(const float4*)&part[off];
    float4 a1 = *(const float4*)&part[off + slab];
    float4 a2 = *(const float4*)&part[off + 2 * slab];
    float4 a3 = *(const float4*)&part[off + 3 * slab];
    float4 a;
    a.x = (a0.x + a1.x) + (a2.x + a3.x);
    a.y = (a0.y + a1.y) + (a2.y + a3.y);
    a.z = (a0.z + a1.z) + (a2.z + a3.z);
    a.w = (a0.w + a1.w) + (a2.w + a3.w);
    float4 sc = *(const float4*)&p4[(size_t)(row & 255) * 256 + lane * 4];
    float4 pv = *(const float4*)&p5[lane * 4];
    float v0 = a.x * sc.x, v1 = a.y * sc.y, v2 = a.z * sc.z, v3 = a.w * sc.w;
    ushort4 o;
    o.x = f2bf(v0); o.y = f2bf(v1); o.z = f2bf(v2); o.w = f2bf(v3);
    *(ushort4*)&t4h[(size_t)row * 256 + lane * 4] = o;
    float sum = v0 * pv.x + v1 * pv.y + v2 * pv.z + v3 * pv.w;
#pragma unroll
    for (int offd = 32; offd > 0; offd >>= 1) sum += __shfl_down(sum, offd);
    if (lane == 0) t5[row] = sum;
}

// ---------------------------------------------------------------------------
// t7[n][s] = (sum_c t5[n*256+c] * xp[n][sp(s)][c]) / 16
// ---------------------------------------------------------------------------
__global__ __launch_bounds__(256) void k_t7(
    const unsigned short* __restrict__ xp, const float* __restrict__ t5,
    float* __restrict__ t7)
{
    const int n = blockIdx.y;
    const int wave = threadIdx.x >> 6, lane = threadIdx.x & 63;
    float4 w = *(const float4*)&t5[n * 256 + lane * 4];
    const int s0 = blockIdx.x * 16 + wave * 4;
#pragma unroll
    for (int qq = 0; qq < 4; ++qq) {
        const int s = s0 + qq;
        const int sp = s + 2 * (s / 56) + 59;
        ushort4 a = *(const ushort4*)&xp[((size_t)n * SPAD + sp) * 256 + lane * 4];
        float sum = bf2f(a.x) * w.x + bf2f(a.y) * w.y + bf2f(a.z) * w.z + bf2f(a.w) * w.w;
#pragma unroll
        for (int off = 32; off > 0; off >>= 1) sum += __shfl_down(sum, off);
        if (lane == 0) t7[n * HWB + s] = sum * 0.0625f;
    }
}

// ---------------------------------------------------------------------------
// BMM: out[n][a][s] = (sum_b t4h[n][a][b] * t3cl[n][s][b]) / 16 + t7[n][s]
// XCD-swizzled 1D grid (same-n blocks share t3cl[n]/t4h[n] in L2);
// double-buffered staging.
// ---------------------------------------------------------------------------
__global__ __launch_bounds__(256) void k_bmm(
    const unsigned short* __restrict__ t4h, const unsigned short* __restrict__ t3cl,
    const float* __restrict__ t7, float* __restrict__ out)
{
    __shared__ short As[2][128 * 64];
    __shared__ short Bs[2][128 * 64];
    const int tid = threadIdx.x;
    const int orig = blockIdx.x;                       // 1600 = 8 * 200
    const int wgid = (orig & 7) * 200 + (orig >> 3);
    const int n = wgid / 50;
    const int rem = wgid - n * 50;
    const int tileA = (rem / 25) * 128;
    const int tileS = (rem % 25) * 128;
    const int wave = tid >> 6, lane = tid & 63;
    const int wm = (wave >> 1) * 64, wn = (wave & 1) * 64;

    const int rl = tid >> 3, q = tid & 7;
    const int swq = (q ^ (rl & 7)) * 8;
    const unsigned short* asrc = t4h + ((size_t)n * 256 + tileA + rl) * 256 + swq;
    const unsigned short* bsrc = t3cl + ((size_t)n * HWPAD + tileS + rl) * 256 + swq;

    f32x4 acc[4][4] = {};
    const int frow = lane & 15, quad = lane >> 4, sw = frow & 7;
    const int ldst = rl * 64 + q * 8;

#pragma unroll
    for (int p = 0; p < 4; ++p) {
        gl_lds16(asrc + (size_t)(p * 32) * 256, &As[0][p * 2048 + ldst]);
        gl_lds16(bsrc + (size_t)(p * 32) * 256, &Bs[0][p * 2048 + ldst]);
    }
    __syncthreads();

    int cur = 0;
#pragma unroll
    for (int k0 = 0; k0 < 256; k0 += 64) {
        if (k0 < 192) {
            const int kn = k0 + 64;
#pragma unroll
            for (int p = 0; p < 4; ++p) {
                gl_lds16(asrc + (size_t)(p * 32) * 256 + kn, &As[cur ^ 1][p * 2048 + ldst]);
                gl_lds16(bsrc + (size_t)(p * 32) * 256 + kn, &Bs[cur ^ 1][p * 2048 + ldst]);
            }
        }
        const short* Ab = As[cur];
        const short* Bb = Bs[cur];
#pragma unroll
        for (int h = 0; h < 2; ++h) {
            bf16x8 af[4], bfr[4];
#pragma unroll
            for (int i = 0; i < 4; ++i)
                af[i] = *(const bf16x8*)&Ab[(wm + i * 16 + frow) * 64 + ((h * 4 + quad) ^ sw) * 8];
#pragma unroll
            for (int j = 0; j < 4; ++j)
                bfr[j] = *(const bf16x8*)&Bb[(wn + j * 16 + frow) * 64 + ((h * 4 + quad) ^ sw) * 8];
#pragma unroll
            for (int i = 0; i < 4; ++i)
#pragma unroll
                for (int j = 0; j < 4; ++j)
                    acc[i][j] = __builtin_amdgcn_mfma_f32_16x16x32_bf16(af[i], bfr[j], acc[i][j], 0, 0, 0);
        }
        __syncthreads();
        cur ^= 1;
    }
    const float* t7n = t7 + (size_t)n * HWB;
    float* ob = out + (size_t)n * 256 * HWB;
#pragma unroll
    for (int j = 0; j < 4; ++j) {
        int s = tileS + wn + j * 16 + (lane & 15);
        bool vsx = s < HWB;
        float t7v = vsx ? t7n[s] : 0.f;
        if (!vsx) continue;
#pragma unroll
        for (int i = 0; i < 4; ++i)
#pragma unroll
            for (int r = 0; r < 4; ++r) {
                int a = tileA + wm + i * 16 + (lane >> 4) * 4 + r;
                ob[(size_t)a * HWB + s] = acc[i][j][r] * 0.0625f + t7v;
            }
    }
}

extern "C" void kernel_launch(void* const* d_in, const int* in_sizes, int n_in,
                              void* d_out, int out_size, void* d_ws, size_t ws_size,
                              hipStream_t stream) {
    const float* x  = (const float*)d_in[0];
    const float* p1 = (const float*)d_in[1];
    const float* cw = (const float*)d_in[2];
    const float* p4 = (const float*)d_in[3];
    const float* p5 = (const float*)d_in[4];

    char* w = (char*)d_ws;
    unsigned short* xp    = (unsigned short*)w;  w += (size_t)32 * SPAD * 256 * 2;   // 55.1 MB
    unsigned short* t3cl  = (unsigned short*)w;  w += (size_t)32 * HWPAD * 256 * 2;  // 52.4 MB
    unsigned short* p1t   = (unsigned short*)w;  w += (size_t)256 * HWB * 2;
    unsigned short* wpack = (unsigned short*)w;  w += (size_t)256 * 1152 * 2;
    unsigned short* t4h   = (unsigned short*)w;  w += (size_t)8192 * 256 * 2;
    float* t5             = (float*)w;           w += (size_t)8192 * 4;
    float* t7             = (float*)w;           w += (size_t)32 * HWB * 4;

    // d_out doubles as scratch before k_bmm finally writes it:
    //   xc   [32][256][3136] bf16 = 51,380,224 B
    //   part [4][8192][256]  f32  = 33,554,432 B  (total 84.9 MB <= 102.8 MB)
    char* o = (char*)d_out;
    unsigned short* xc = (unsigned short*)o;
    float* part        = (float*)(o + (size_t)32 * 256 * HWB * 2);
    float* out = (float*)d_out;

    k_prep    <<<dim3(98, 8, 32), 256, 0, stream>>>(x, xc, xp);
    k_prep_p1t<<<dim3(98, 8),     256, 0, stream>>>(p1, p1t);
    k_prep_w  <<<dim3(256),       256, 0, stream>>>(cw, wpack, xp);
    k_conv    <<<dim3(1600),      256, 0, stream>>>(xp, wpack, t3cl);
    k_gemm1   <<<dim3(512),       256, 0, stream>>>(xc, p1t, part);
    k_t4scale <<<dim3(2048),      256, 0, stream>>>(part, p4, p5, t4h, t5);
    k_t7      <<<dim3(196, 32),   256, 0, stream>>>(xp, t5, t7);
    k_bmm     <<<dim3(1600),      256, 0, stream>>>(t4h, t3cl, t7, out);
}